// Round 3
// baseline (1594.400 us; speedup 1.0000x reference)
//
#include <hip/hip_runtime.h>
#include <math.h>

#define NUM_C   1000
#define MOM     0.9f
#define EPS     1e-6f

// Fused kernel: per-row CE + per-class atomic stats + last-block finalize.
// One wave (64 lanes) per row, 4 waves per 256-thread block. 250 float4 per
// row; each lane holds up to 4 float4 in registers. Wave-reduce max, then
// wave-reduce {sum(exp(x-m)), logit_at_target}. Lane 0 atomics into per-class
// sums/counts. The last block to finish (ticket) computes the final scalar:
//   out = [sum_c sums_c * w_c] / [sum_c cnt_c * w_c],  w_c = 1/(new_gm_c+eps)
__global__ __launch_bounds__(256) void fused_kernel(const float* __restrict__ logits,
                                                    const int*   __restrict__ targets,
                                                    const float* __restrict__ gm,
                                                    float* __restrict__ sums,
                                                    float* __restrict__ counts,
                                                    unsigned int* __restrict__ ticket,
                                                    float* __restrict__ out,
                                                    int n, unsigned int nblocks) {
    const int wave = threadIdx.x >> 6;
    const int lane = threadIdx.x & 63;
    const int row  = blockIdx.x * 4 + wave;
    const bool active = (row < n);

    if (active) {
        const int t  = targets[row];    // wave-uniform -> one line, broadcast
        const int tq = t >> 2;
        const int tc = t & 3;

        const float4* rp = reinterpret_cast<const float4*>(logits + (size_t)row * NUM_C);

        float4 v[4];
        float m = -INFINITY;
#pragma unroll
        for (int j = 0; j < 4; ++j) {
            int idx = j * 64 + lane;
            if (idx < 250) {
                v[j] = rp[idx];
                m = fmaxf(m, fmaxf(fmaxf(v[j].x, v[j].y), fmaxf(v[j].z, v[j].w)));
            }
        }
#pragma unroll
        for (int off = 32; off > 0; off >>= 1)
            m = fmaxf(m, __shfl_xor(m, off, 64));

        float s  = 0.f;   // sum of exp(x - m)
        float lt = 0.f;   // logit at target (owning lane contributes)
#pragma unroll
        for (int j = 0; j < 4; ++j) {
            int idx = j * 64 + lane;
            if (idx < 250) {
                s += __expf(v[j].x - m);
                s += __expf(v[j].y - m);
                s += __expf(v[j].z - m);
                s += __expf(v[j].w - m);
                if (idx == tq) {
                    lt = (tc == 0) ? v[j].x : (tc == 1) ? v[j].y
                       : (tc == 2) ? v[j].z : v[j].w;
                }
            }
        }
#pragma unroll
        for (int off = 32; off > 0; off >>= 1) {
            s  += __shfl_xor(s,  off, 64);
            lt += __shfl_xor(lt, off, 64);
        }

        if (lane == 0) {
            float ce = (m + __logf(s)) - lt;   // -log_softmax at target
            atomicAdd(&sums[t], ce);
            atomicAdd(&counts[t], 1.0f);
            __threadfence();                   // release our atomics device-wide
        }
    }

    // ---- last-block ticket ----
    __shared__ unsigned int isLast;
    __syncthreads();                           // all waves' atomics issued+fenced
    if (threadIdx.x == 0) {
        unsigned int old = atomicAdd(ticket, 1u);
        isLast = (old == nblocks - 1) ? 1u : 0u;
    }
    __syncthreads();
    if (!isLast) return;

    // ---- finalize (one block, 256 threads, 4 classes each) ----
    __threadfence();
    float a = 0.f, b = 0.f;
    for (int c = threadIdx.x; c < NUM_C; c += 256) {
        float cnt = atomicAdd(&counts[c], 0.0f);   // device-coherent read
        float s   = atomicAdd(&sums[c],   0.0f);
        float g   = gm[c];
        if (cnt > 0.f) {
            float cm = fabsf(s / fmaxf(cnt, 1.0f));
            g = MOM * g + (1.0f - MOM) * cm;
        }
        float w = 1.0f / (g + EPS);
        a += cnt * w;
        b += s * w;
    }
#pragma unroll
    for (int off = 32; off > 0; off >>= 1) {
        a += __shfl_xor(a, off, 64);
        b += __shfl_xor(b, off, 64);
    }
    __shared__ float sa[4], sb[4];
    if (lane == 0) { sa[wave] = a; sb[wave] = b; }
    __syncthreads();
    if (threadIdx.x == 0) {
        float A = sa[0] + sa[1] + sa[2] + sa[3];
        float B = sb[0] + sb[1] + sb[2] + sb[3];
        out[0] = B / A;
    }
}

extern "C" void kernel_launch(void* const* d_in, const int* in_sizes, int n_in,
                              void* d_out, int out_size, void* d_ws, size_t ws_size,
                              hipStream_t stream) {
    const float* logits  = (const float*)d_in[0];
    const int*   targets = (const int*)d_in[1];
    const float* gm      = (const float*)d_in[2];
    float* out = (float*)d_out;

    const int n = in_sizes[1];  // number of rows / targets

    float* sums           = (float*)d_ws;            // NUM_C
    float* counts         = sums + NUM_C;            // NUM_C
    unsigned int* ticket  = (unsigned int*)(counts + NUM_C);  // 1

    // zero sums, counts, ticket every call (accumulated via atomics)
    hipMemsetAsync(sums, 0, 2 * NUM_C * sizeof(float) + sizeof(unsigned int), stream);

    const unsigned int nblocks = (n + 3) / 4;
    fused_kernel<<<nblocks, 256, 0, stream>>>(logits, targets, gm, sums, counts,
                                              ticket, out, n, nblocks);
}

// Round 4
// 54.985 us; speedup vs baseline: 28.9968x; 28.9968x over previous
//
#include <hip/hip_runtime.h>
#include <math.h>

#define NUM_C   1000
#define MOM     0.9f
#define EPS     1e-6f

// ---------------- kernel 1: per-row CE (online softmax) + per-class atomics --
// One wave (64 lanes) per row, 4 waves per 256-thread block. 250 float4 per
// row. Single pass: each float4 is consumed immediately after load (chunk max,
// rescale running (m,s)) so no data stays live across phases -> low VGPR, no
// compiler reload of logits. Butterfly-merge (m,s) pairs across the 64 lanes.
// NOTE (R3 lesson): no __threadfence / last-block fusion — device-scope fences
// on gfx950 emit L2 writebacks and serialized the whole kernel (30x slower).
__global__ __launch_bounds__(256) void ce_kernel(const float* __restrict__ logits,
                                                 const int*   __restrict__ targets,
                                                 float* __restrict__ sums,
                                                 float* __restrict__ counts,
                                                 int n) {
    const int wave = threadIdx.x >> 6;
    const int lane = threadIdx.x & 63;
    const int row  = blockIdx.x * 4 + wave;
    if (row >= n) return;

    const int t  = targets[row];        // wave-uniform -> one line, broadcast
    const int tq = t >> 2;              // float4 index holding the target
    const int tc = t & 3;

    const float4* rp = reinterpret_cast<const float4*>(logits + (size_t)row * NUM_C);

    float m  = -INFINITY;   // running max
    float s  = 0.f;         // running sum of exp(x - m)
    float lt = 0.f;         // logit at target (owning lane contributes)

#pragma unroll
    for (int j = 0; j < 4; ++j) {
        int idx = j * 64 + lane;
        if (idx < 250) {
            float4 v = rp[idx];
            float cm = fmaxf(fmaxf(v.x, v.y), fmaxf(v.z, v.w));
            float M  = fmaxf(m, cm);
            // rescale old sum; exp(-inf - M) = 0 handles the first chunk
            s = s * __expf(m - M)
              + __expf(v.x - M) + __expf(v.y - M)
              + __expf(v.z - M) + __expf(v.w - M);
            m = M;
            if (idx == tq) {
                lt = (tc == 0) ? v.x : (tc == 1) ? v.y
                   : (tc == 2) ? v.z : v.w;
            }
        }
    }

    // butterfly merge of (m, s) pairs + sum of lt across 64 lanes
#pragma unroll
    for (int off = 32; off > 0; off >>= 1) {
        float om = __shfl_xor(m, off, 64);
        float os = __shfl_xor(s, off, 64);
        float M  = fmaxf(m, om);
        s = s * __expf(m - M) + os * __expf(om - M);
        m = M;
        lt += __shfl_xor(lt, off, 64);
    }

    if (lane == 0) {
        float ce = (m + __logf(s)) - lt;   // -log_softmax at target
        atomicAdd(&sums[t], ce);
        atomicAdd(&counts[t], 1.0f);
    }
}

// ---------------- kernel 2: EMA + weighted ratio, fused ----------------
// out = [sum_c sums_c * w_c] / [sum_c cnt_c * w_c],  w_c = 1/(new_gm_c + eps)
// One block of 256 threads, 4 classes per thread; block reduce; no atomics.
__global__ __launch_bounds__(256) void finalize_kernel(const float* __restrict__ gm_in,
                                                       const float* __restrict__ sums,
                                                       const float* __restrict__ counts,
                                                       float* __restrict__ out) {
    float a = 0.f, b = 0.f;
    for (int c = threadIdx.x; c < NUM_C; c += 256) {
        float cnt = counts[c];
        float s   = sums[c];
        float g   = gm_in[c];
        if (cnt > 0.f) {
            float cm = fabsf(s / fmaxf(cnt, 1.0f));
            g = MOM * g + (1.0f - MOM) * cm;
        }
        float w = 1.0f / (g + EPS);
        a += cnt * w;   // sum of per-sample weights in this class
        b += s * w;     // sum of w * ce in this class
    }
#pragma unroll
    for (int off = 32; off > 0; off >>= 1) {
        a += __shfl_xor(a, off, 64);
        b += __shfl_xor(b, off, 64);
    }
    __shared__ float sa[4], sb[4];
    const int lane = threadIdx.x & 63;
    const int wv   = threadIdx.x >> 6;
    if (lane == 0) { sa[wv] = a; sb[wv] = b; }
    __syncthreads();
    if (threadIdx.x == 0) {
        out[0] = (sb[0] + sb[1] + sb[2] + sb[3])
               / (sa[0] + sa[1] + sa[2] + sa[3]);
    }
}

extern "C" void kernel_launch(void* const* d_in, const int* in_sizes, int n_in,
                              void* d_out, int out_size, void* d_ws, size_t ws_size,
                              hipStream_t stream) {
    const float* logits  = (const float*)d_in[0];
    const int*   targets = (const int*)d_in[1];
    const float* gm      = (const float*)d_in[2];
    float* out = (float*)d_out;

    const int n = in_sizes[1];  // number of rows / targets

    float* sums   = (float*)d_ws;       // NUM_C
    float* counts = sums + NUM_C;       // NUM_C

    hipMemsetAsync(sums, 0, 2 * NUM_C * sizeof(float), stream);

    ce_kernel<<<(n + 3) / 4, 256, 0, stream>>>(logits, targets, sums, counts, n);
    finalize_kernel<<<1, 256, 0, stream>>>(gm, sums, counts, out);
}